// Round 1
// baseline (203.658 us; speedup 1.0000x reference)
//
#include <hip/hip_runtime.h>
#include <stdint.h>

#define B_   16384
#define D_   512
#define N1_  1024   // 2D
#define K1_  512    // D
#define N2_  512
#define K2_  1024

#define DELTA     4e-3f
#define LIST_CAP  (1u << 21)   // global borderline list: 2M entries, 8 MB
#define LCAP      2048u        // per-block LDS list (expected ~208 hits/block)

typedef _Float16 f16x8 __attribute__((ext_vector_type(8)));
typedef _Float16 f16x4 __attribute__((ext_vector_type(4)));
typedef float    f32x4 __attribute__((ext_vector_type(4)));

// ---------------- prep: weights + biases + cvec (z is converted inside fused) ----------------
__global__ __launch_bounds__(256) void prep_w(
    const float* __restrict__ t,
    const float* __restrict__ W1, const float* __restrict__ b1,
    const float* __restrict__ W2, const float* __restrict__ b2,
    _Float16* __restrict__ w1h, _Float16* __restrict__ w2h,
    float* __restrict__ bias1, float* __restrict__ bias2,
    float* __restrict__ cvec, uint32_t* __restrict__ counter) {
  int blk = blockIdx.x, tid = threadIdx.x;
  if (blk < 2048) {                                 // W1 -> w1h (1024x512 f16, x64)
    int idx = blk * 256 + tid;                      // [0, 524288)
    int j = idx >> 9, k = idx & 511;
    w1h[idx] = (_Float16)(W1[(size_t)j * 513 + k] * 64.f);
  } else if (blk < 4096) {                          // W2 -> w2h (512x1024 f16)
    int idx = (blk - 2048) * 256 + tid;
    int i = idx >> 10, j = idx & 1023;
    w2h[idx] = (_Float16)W2[(size_t)i * 1025 + j];
  } else if (blk < 4100) {                          // biases + counter
    int j = (blk - 4096) * 256 + tid;               // [0, 1024)
    float t0 = t[0];
    bias1[j] = b1[j] + t0 * W1[(size_t)j * 513 + 512];
    if (j < 512) bias2[j] = b2[j] + t0 * W2[(size_t)j * 1025 + 1024];
    if (j == 0) *counter = 0;
  } else {                                          // c[j] = sum_k W2[k,j]*W1[j,k]
    int wave = tid >> 6, lane = tid & 63;
    int j = (blk - 4100) * 4 + wave;                // [0, 1024)
    float s = 0.f;
    #pragma unroll
    for (int kk = 0; kk < 8; ++kk) {
      int k = lane + kk * 64;
      s += W2[(size_t)k * 1025 + j] * W1[(size_t)j * 513 + k];
    }
    #pragma unroll
    for (int off = 32; off > 0; off >>= 1) s += __shfl_xor(s, off);
    if (lane == 0) cvec[j] = s;
  }
}

// ---------------- fused: h = relu(z@W1^T+b1) in LDS chunks, dz = h@W2^T+b2, trace ----------------
// Block = 64 z-rows, 512 threads (8 waves, 2/SIMD), grid = 256 (1 block/CU).
// Both MFMAs use SWAPPED operands: mfma(W_frag, act_frag) so D: col(lane&15)=z-row,
// row(q*4+reg)=output col -> 4 consecutive output cols per thread (b64 LDS h-writes,
// f32x4 coalesced dz stores). LDS tiles XOR-swizzled: granule16 ^= (row&7) -> no bank
// conflicts on ds_read_b128. No barriers inside the K loops; 2 barriers per chunk x2.

__global__ __launch_bounds__(512, 2) void fused_kernel(
    const float* __restrict__ z,
    const _Float16* __restrict__ w1h, const _Float16* __restrict__ w2h,
    const float* __restrict__ bias1, const float* __restrict__ bias2,
    const float* __restrict__ cvec,
    float* __restrict__ out, float* __restrict__ dlogp,
    uint32_t* __restrict__ list, uint32_t* __restrict__ counter) {
  __shared__ __align__(16) _Float16 Az[64 * 512];   // 64 KB, swizzled z tile (x16, f16)
  __shared__ __align__(16) _Float16 Hb[64 * 512];   // 64 KB, swizzled h chunk (512 cols)
  __shared__ uint32_t llist[LCAP];                  // 8 KB
  __shared__ float redbuf[8][64];                   // 2 KB trace reduce
  __shared__ uint32_t lcnt, lbase;

  const int tid  = threadIdx.x;
  const int lane = tid & 63, w = tid >> 6;          // wave id 0..7
  const int q    = lane >> 4, m16 = lane & 15;
  const int sw   = m16 & 7;                         // swizzle key (row&7 == m16&7)
  const int bm   = blockIdx.x;                      // 256 blocks, 64 rows each

  if (tid == 0) lcnt = 0;

  // ---- stage z (f32 -> f16 x16) into swizzled Az; 64x512 f16 = 64KB ----
  {
    const float* zp = z + (size_t)bm * 64 * 512;
    #pragma unroll
    for (int i = 0; i < 16; ++i) {
      int slot = i * 512 + tid;                     // 8B units: row = slot/128
      int row = slot >> 7, u8 = slot & 127;
      f32x4 v = *(const f32x4*)(zp + (size_t)row * 512 + u8 * 4);
      f16x4 hv;
      #pragma unroll
      for (int r = 0; r < 4; ++r) hv[r] = (_Float16)(v[r] * 16.f);
      int gp = (u8 >> 1) ^ (row & 7);
      *(f16x4*)((char*)Az + row * 1024 + gp * 16 + (u8 & 1) * 8) = hv;
    }
  }
  __syncthreads();

  float tr[4] = {0.f, 0.f, 0.f, 0.f};
  f32x4 acc2[4][4] = {};                            // dz accum: [mt(row tile)][nt(col tile)]
  const char* azb = (const char*)Az + m16 * 1024;
  const char* hbb = (const char*)Hb + m16 * 1024;
  char*       hbw = (char*)Hb;

  for (int ch = 0; ch < 2; ++ch) {                  // 2 chunks of 512 h-cols
    // ---- GEMM1: h_pre chunk. Wave w owns h-cols [ch*512 + w*64, +64), all 64 rows ----
    f32x4 acc1[4][4] = {};                          // [mt(z-row tile)][nt(h-col tile)]
    const _Float16* w1base = w1h + (size_t)(ch * 512 + w * 64 + m16) * 512 + q * 8;
    f16x8 wf[4];
    #pragma unroll
    for (int nt = 0; nt < 4; ++nt) wf[nt] = *(const f16x8*)(w1base + nt * 8192);
    #pragma unroll
    for (int ks = 0; ks < 16; ++ks) {               // K = 512, 32 per slice
      f16x8 cw[4], zf[4];
      #pragma unroll
      for (int nt = 0; nt < 4; ++nt) {
        cw[nt] = wf[nt];
        if (ks < 15) wf[nt] = *(const f16x8*)(w1base + nt * 8192 + (ks + 1) * 32);
      }
      #pragma unroll
      for (int mt = 0; mt < 4; ++mt)
        zf[mt] = *(const f16x8*)(azb + mt * 16384 + (((ks * 4 + q) ^ sw) << 4));
      __builtin_amdgcn_s_setprio(1);
      #pragma unroll
      for (int nt = 0; nt < 4; ++nt)
        #pragma unroll
        for (int mt = 0; mt < 4; ++mt)
          acc1[mt][nt] = __builtin_amdgcn_mfma_f32_16x16x32_f16(cw[nt], zf[mt], acc1[mt][nt], 0, 0, 0);
      __builtin_amdgcn_s_setprio(0);
    }

    // ---- epilogue: bias+relu, trace, borderline list, write h chunk to LDS ----
    #pragma unroll
    for (int nt = 0; nt < 4; ++nt) {
      int colc = w * 64 + nt * 16 + q * 4;          // chunk-local col (4 consecutive per thread)
      f32x4 b4 = *(const f32x4*)(bias1 + ch * 512 + colc);
      f32x4 c4 = *(const f32x4*)(cvec  + ch * 512 + colc);
      #pragma unroll
      for (int mt = 0; mt < 4; ++mt) {
        int row = mt * 16 + m16;
        f16x4 hv;
        #pragma unroll
        for (int r = 0; r < 4; ++r) {
          float hp = acc1[mt][nt][r] * (1.f / 1024.f) + b4[r];
          hv[r] = (_Float16)(hp > 0.f ? hp : 0.f);
          if (hp > 0.f) tr[mt] += c4[r];
          if (__builtin_fabsf(hp) < DELTA) {
            uint32_t i = atomicAdd(&lcnt, 1u);      // LDS atomic: cheap
            if (i < LCAP)
              llist[i] = ((uint32_t)(bm * 64 + row) << 10) | (uint32_t)(ch * 512 + colc + r) |
                         (hp > 0.f ? 0x80000000u : 0u);
          }
        }
        int gp = ((colc >> 3) ^ (row & 7));
        *(f16x4*)(hbw + row * 1024 + gp * 16 + (q & 1) * 8) = hv;
      }
    }
    __syncthreads();                                // h chunk complete

    // ---- GEMM2 partial: dz += h_chunk @ W2[:, chunk]^T. Wave w owns dz cols [w*64,+64) ----
    {
      const _Float16* w2base = w2h + (size_t)(w * 64 + m16) * 1024 + ch * 512 + q * 8;
      f16x8 wf2[4];
      #pragma unroll
      for (int nt = 0; nt < 4; ++nt) wf2[nt] = *(const f16x8*)(w2base + nt * 16384);
      #pragma unroll
      for (int ks = 0; ks < 16; ++ks) {             // k-slab = 512 this chunk
        f16x8 cw[4], hf[4];
        #pragma unroll
        for (int nt = 0; nt < 4; ++nt) {
          cw[nt] = wf2[nt];
          if (ks < 15) wf2[nt] = *(const f16x8*)(w2base + nt * 16384 + (ks + 1) * 32);
        }
        #pragma unroll
        for (int mt = 0; mt < 4; ++mt)
          hf[mt] = *(const f16x8*)(hbb + mt * 16384 + (((ks * 4 + q) ^ sw) << 4));
        __builtin_amdgcn_s_setprio(1);
        #pragma unroll
        for (int nt = 0; nt < 4; ++nt)
          #pragma unroll
          for (int mt = 0; mt < 4; ++mt)
            acc2[mt][nt] = __builtin_amdgcn_mfma_f32_16x16x32_f16(cw[nt], hf[mt], acc2[mt][nt], 0, 0, 0);
        __builtin_amdgcn_s_setprio(0);
      }
    }
    __syncthreads();                                // Hb reads done before next chunk rewrites
  }

  // ---- dz store: +bias2, coalesced f32x4 (4 consecutive cols per thread) ----
  #pragma unroll
  for (int mt = 0; mt < 4; ++mt) {
    int row = bm * 64 + mt * 16 + m16;
    #pragma unroll
    for (int nt = 0; nt < 4; ++nt) {
      int col = w * 64 + nt * 16 + q * 4;
      f32x4 b2v = *(const f32x4*)(bias2 + col);
      f32x4 v = acc2[mt][nt] + b2v;
      *(f32x4*)(out + (size_t)row * 512 + col) = v;
    }
  }

  // ---- trace: block-local, deterministic (no global atomics) ----
  #pragma unroll
  for (int mt = 0; mt < 4; ++mt) {
    tr[mt] += __shfl_xor(tr[mt], 16);
    tr[mt] += __shfl_xor(tr[mt], 32);
  }
  if (q == 0) {
    #pragma unroll
    for (int mt = 0; mt < 4; ++mt) redbuf[w][mt * 16 + m16] = tr[mt];
  }
  __syncthreads();
  if (tid < 64) {
    float s = 0.f;
    #pragma unroll
    for (int ww = 0; ww < 8; ++ww) s += redbuf[ww][tid];
    dlogp[bm * 64 + tid] = -s;
  }

  // ---- flush borderline list: ONE device atomic per block ----
  if (tid == 0) {
    uint32_t n = lcnt < LCAP ? lcnt : LCAP;
    lbase = atomicAdd(counter, n);
  }
  __syncthreads();
  uint32_t n = lcnt < LCAP ? lcnt : LCAP;
  uint32_t base = lbase;
  for (uint32_t i = tid; i < n; i += 512) {
    uint32_t gi = base + i;
    if (gi < LIST_CAP) list[gi] = llist[i];
  }
}

// ---------------- fixup: recompute borderline h_pre in fp32, patch dlogp ----------------
__global__ __launch_bounds__(256)
void fixup_kernel(const float* __restrict__ z, const float* __restrict__ W1,
                  const float* __restrict__ bias1, const float* __restrict__ cvec,
                  const uint32_t* __restrict__ list, const uint32_t* __restrict__ counter,
                  float* __restrict__ dlogp) {
  uint32_t cnt = *counter;
  if (cnt > LIST_CAP) cnt = LIST_CAP;
  const int wid = (blockIdx.x * 256 + threadIdx.x) >> 6;
  const int lane = threadIdx.x & 63;
  const int nw = gridDim.x * 4;
  for (uint32_t i = wid; i < cnt; i += nw) {
    uint32_t e = list[i];
    int row = (int)((e >> 10) & 16383u);
    int col = (int)(e & 1023u);
    int oldm = (int)(e >> 31);
    float s = 0.f;
    #pragma unroll
    for (int it = 0; it < 8; ++it) {
      int k = it * 64 + lane;
      s += z[(size_t)row * 512 + k] * W1[(size_t)col * 513 + k];
    }
    #pragma unroll
    for (int off = 32; off > 0; off >>= 1) s += __shfl_xor(s, off);
    if (lane == 0) {
      float hp = s + bias1[col];
      int newm = hp > 0.f ? 1 : 0;
      if (newm != oldm)
        atomicAdd(&dlogp[row], oldm ? cvec[col] : -cvec[col]);
    }
  }
}

// ---------------- launcher ----------------
extern "C" void kernel_launch(void* const* d_in, const int* in_sizes, int n_in,
                              void* d_out, int out_size, void* d_ws, size_t ws_size,
                              hipStream_t stream) {
  const float* t  = (const float*)d_in[0];
  const float* z  = (const float*)d_in[1];
  // d_in[2] = logp_z, unused
  const float* W1 = (const float*)d_in[3];
  const float* b1 = (const float*)d_in[4];
  const float* W2 = (const float*)d_in[5];
  const float* b2 = (const float*)d_in[6];

  float* out   = (float*)d_out;
  float* dlogp = out + (size_t)B_ * D_;

  char* ws = (char*)d_ws;
  _Float16* w1h   = (_Float16*)ws; ws += (size_t)N1_ * K1_ * 2;  // 1 MB
  _Float16* w2h   = (_Float16*)ws; ws += (size_t)N2_ * K2_ * 2;  // 1 MB
  float*    bias1 = (float*)ws;    ws += 1024 * 4;
  float*    bias2 = (float*)ws;    ws += 512 * 4;
  float*    cvec  = (float*)ws;    ws += 1024 * 4;
  uint32_t* counter = (uint32_t*)ws; ws += 256;
  uint32_t* list  = (uint32_t*)ws; ws += (size_t)LIST_CAP * 4;   // 8 MB

  prep_w<<<4356, 256, 0, stream>>>(t, W1, b1, W2, b2, w1h, w2h, bias1, bias2, cvec, counter);
  fused_kernel<<<256, 512, 0, stream>>>(z, w1h, w2h, bias1, bias2, cvec, out, dlogp, list, counter);
  fixup_kernel<<<2048, 256, 0, stream>>>(z, W1, bias1, cvec, list, counter, dlogp);
}

// Round 2
// 201.717 us; speedup vs baseline: 1.0096x; 1.0096x over previous
//
#include <hip/hip_runtime.h>
#include <stdint.h>

#define B_   16384
#define D_   512
#define N1_  1024   // 2D
#define K1_  512    // D
#define N2_  512
#define K2_  1024

#define DELTA     4e-3f
#define LIST_CAP  (1u << 21)   // global borderline list: 2M entries, 8 MB
#define LCAP      2048u        // per-block LDS list (expected ~208 hits/block)

typedef _Float16 f16x8 __attribute__((ext_vector_type(8)));
typedef _Float16 f16x4 __attribute__((ext_vector_type(4)));
typedef float    f32x4 __attribute__((ext_vector_type(4)));

// ---------------- prep: weights + biases + cvec (z is converted inside fused) ----------------
__global__ __launch_bounds__(256) void prep_w(
    const float* __restrict__ t,
    const float* __restrict__ W1, const float* __restrict__ b1,
    const float* __restrict__ W2, const float* __restrict__ b2,
    _Float16* __restrict__ w1h, _Float16* __restrict__ w2h,
    float* __restrict__ bias1, float* __restrict__ bias2,
    float* __restrict__ cvec, uint32_t* __restrict__ counter) {
  int blk = blockIdx.x, tid = threadIdx.x;
  if (blk < 2048) {                                 // W1 -> w1h (1024x512 f16, x64)
    int idx = blk * 256 + tid;                      // [0, 524288)
    int j = idx >> 9, k = idx & 511;
    w1h[idx] = (_Float16)(W1[(size_t)j * 513 + k] * 64.f);
  } else if (blk < 4096) {                          // W2 -> w2h (512x1024 f16)
    int idx = (blk - 2048) * 256 + tid;
    int i = idx >> 10, j = idx & 1023;
    w2h[idx] = (_Float16)W2[(size_t)i * 1025 + j];
  } else if (blk < 4100) {                          // biases + counter
    int j = (blk - 4096) * 256 + tid;               // [0, 1024)
    float t0 = t[0];
    bias1[j] = b1[j] + t0 * W1[(size_t)j * 513 + 512];
    if (j < 512) bias2[j] = b2[j] + t0 * W2[(size_t)j * 1025 + 1024];
    if (j == 0) *counter = 0;
  } else {                                          // c[j] = sum_k W2[k,j]*W1[j,k]
    int wave = tid >> 6, lane = tid & 63;
    int j = (blk - 4100) * 4 + wave;                // [0, 1024)
    float s = 0.f;
    #pragma unroll
    for (int kk = 0; kk < 8; ++kk) {
      int k = lane + kk * 64;
      s += W2[(size_t)k * 1025 + j] * W1[(size_t)j * 513 + k];
    }
    #pragma unroll
    for (int off = 32; off > 0; off >>= 1) s += __shfl_xor(s, off);
    if (lane == 0) cvec[j] = s;
  }
}

// ---------------- fused: h = relu(z@W1^T+b1) in LDS chunks, dz = h@W2^T+b2, trace ----------------
// Block = 64 z-rows, 512 threads (8 waves, 2/SIMD), grid = 256 (1 block/CU).
// LDS 138.5KB forces 1 block/CU -> 2 waves/EU is the occupancy ceiling. Pin it:
// amdgpu_waves_per_eu(2,2) gives the allocator the full 256-VGPR budget (demand ~190),
// eliminating the in-loop accumulator spills the 128-VGPR/4-wave heuristic caused.

__global__ __launch_bounds__(512) __attribute__((amdgpu_waves_per_eu(2, 2)))
void fused_kernel(
    const float* __restrict__ z,
    const _Float16* __restrict__ w1h, const _Float16* __restrict__ w2h,
    const float* __restrict__ bias1, const float* __restrict__ bias2,
    const float* __restrict__ cvec,
    float* __restrict__ out, float* __restrict__ dlogp,
    uint32_t* __restrict__ list, uint32_t* __restrict__ counter) {
  __shared__ __align__(16) _Float16 Az[64 * 512];   // 64 KB, swizzled z tile (x16, f16)
  __shared__ __align__(16) _Float16 Hb[64 * 512];   // 64 KB, swizzled h chunk (512 cols)
  __shared__ uint32_t llist[LCAP];                  // 8 KB
  __shared__ float redbuf[8][64];                   // 2 KB trace reduce
  __shared__ uint32_t lcnt, lbase;

  const int tid  = threadIdx.x;
  const int lane = tid & 63, w = tid >> 6;          // wave id 0..7
  const int q    = lane >> 4, m16 = lane & 15;
  const int sw   = m16 & 7;                         // swizzle key (row&7 == m16&7)
  const int bm   = blockIdx.x;                      // 256 blocks, 64 rows each

  if (tid == 0) lcnt = 0;

  // ---- stage z (f32 -> f16 x16) into swizzled Az; 64x512 f16 = 64KB ----
  {
    const float* zp = z + (size_t)bm * 64 * 512;
    #pragma unroll
    for (int i = 0; i < 16; ++i) {
      int slot = i * 512 + tid;                     // 8B units: row = slot/128
      int row = slot >> 7, u8 = slot & 127;
      f32x4 v = *(const f32x4*)(zp + (size_t)row * 512 + u8 * 4);
      f16x4 hv;
      #pragma unroll
      for (int r = 0; r < 4; ++r) hv[r] = (_Float16)(v[r] * 16.f);
      int gp = (u8 >> 1) ^ (row & 7);
      *(f16x4*)((char*)Az + row * 1024 + gp * 16 + (u8 & 1) * 8) = hv;
    }
  }
  __syncthreads();

  float tr[4] = {0.f, 0.f, 0.f, 0.f};
  f32x4 acc2[4][4] = {};                            // dz accum: [mt(row tile)][nt(col tile)]
  const char* azb = (const char*)Az + m16 * 1024;
  const char* hbb = (const char*)Hb + m16 * 1024;
  char*       hbw = (char*)Hb;

  for (int ch = 0; ch < 2; ++ch) {                  // 2 chunks of 512 h-cols
    // ---- GEMM1: h_pre chunk. Wave w owns h-cols [ch*512 + w*64, +64), all 64 rows ----
    f32x4 acc1[4][4] = {};                          // [mt(z-row tile)][nt(h-col tile)]
    const _Float16* w1base = w1h + (size_t)(ch * 512 + w * 64 + m16) * 512 + q * 8;
    f16x8 wf[4];
    #pragma unroll
    for (int nt = 0; nt < 4; ++nt) wf[nt] = *(const f16x8*)(w1base + nt * 8192);
    #pragma unroll
    for (int ks = 0; ks < 16; ++ks) {               // K = 512, 32 per slice
      f16x8 cw[4], zf[4];
      #pragma unroll
      for (int nt = 0; nt < 4; ++nt) {
        cw[nt] = wf[nt];
        if (ks < 15) wf[nt] = *(const f16x8*)(w1base + nt * 8192 + (ks + 1) * 32);
      }
      #pragma unroll
      for (int mt = 0; mt < 4; ++mt)
        zf[mt] = *(const f16x8*)(azb + mt * 16384 + (((ks * 4 + q) ^ sw) << 4));
      __builtin_amdgcn_s_setprio(1);
      #pragma unroll
      for (int nt = 0; nt < 4; ++nt)
        #pragma unroll
        for (int mt = 0; mt < 4; ++mt)
          acc1[mt][nt] = __builtin_amdgcn_mfma_f32_16x16x32_f16(cw[nt], zf[mt], acc1[mt][nt], 0, 0, 0);
      __builtin_amdgcn_s_setprio(0);
    }

    // ---- epilogue: bias+relu, trace, borderline list, write h chunk to LDS ----
    #pragma unroll
    for (int nt = 0; nt < 4; ++nt) {
      int colc = w * 64 + nt * 16 + q * 4;          // chunk-local col (4 consecutive per thread)
      f32x4 b4 = *(const f32x4*)(bias1 + ch * 512 + colc);
      f32x4 c4 = *(const f32x4*)(cvec  + ch * 512 + colc);
      #pragma unroll
      for (int mt = 0; mt < 4; ++mt) {
        int row = mt * 16 + m16;
        f16x4 hv;
        #pragma unroll
        for (int r = 0; r < 4; ++r) {
          float hp = acc1[mt][nt][r] * (1.f / 1024.f) + b4[r];
          hv[r] = (_Float16)(hp > 0.f ? hp : 0.f);
          if (hp > 0.f) tr[mt] += c4[r];
          if (__builtin_fabsf(hp) < DELTA) {
            uint32_t i = atomicAdd(&lcnt, 1u);      // LDS atomic: cheap
            if (i < LCAP)
              llist[i] = ((uint32_t)(bm * 64 + row) << 10) | (uint32_t)(ch * 512 + colc + r) |
                         (hp > 0.f ? 0x80000000u : 0u);
          }
        }
        int gp = ((colc >> 3) ^ (row & 7));
        *(f16x4*)(hbw + row * 1024 + gp * 16 + (q & 1) * 8) = hv;
      }
    }
    __syncthreads();                                // h chunk complete

    // ---- GEMM2 partial: dz += h_chunk @ W2[:, chunk]^T. Wave w owns dz cols [w*64,+64) ----
    {
      const _Float16* w2base = w2h + (size_t)(w * 64 + m16) * 1024 + ch * 512 + q * 8;
      f16x8 wf2[4];
      #pragma unroll
      for (int nt = 0; nt < 4; ++nt) wf2[nt] = *(const f16x8*)(w2base + nt * 16384);
      #pragma unroll
      for (int ks = 0; ks < 16; ++ks) {             // k-slab = 512 this chunk
        f16x8 cw[4], hf[4];
        #pragma unroll
        for (int nt = 0; nt < 4; ++nt) {
          cw[nt] = wf2[nt];
          if (ks < 15) wf2[nt] = *(const f16x8*)(w2base + nt * 16384 + (ks + 1) * 32);
        }
        #pragma unroll
        for (int mt = 0; mt < 4; ++mt)
          hf[mt] = *(const f16x8*)(hbb + mt * 16384 + (((ks * 4 + q) ^ sw) << 4));
        __builtin_amdgcn_s_setprio(1);
        #pragma unroll
        for (int nt = 0; nt < 4; ++nt)
          #pragma unroll
          for (int mt = 0; mt < 4; ++mt)
            acc2[mt][nt] = __builtin_amdgcn_mfma_f32_16x16x32_f16(cw[nt], hf[mt], acc2[mt][nt], 0, 0, 0);
        __builtin_amdgcn_s_setprio(0);
      }
    }
    __syncthreads();                                // Hb reads done before next chunk rewrites
  }

  // ---- dz store: +bias2, coalesced f32x4 (4 consecutive cols per thread) ----
  #pragma unroll
  for (int mt = 0; mt < 4; ++mt) {
    int row = bm * 64 + mt * 16 + m16;
    #pragma unroll
    for (int nt = 0; nt < 4; ++nt) {
      int col = w * 64 + nt * 16 + q * 4;
      f32x4 b2v = *(const f32x4*)(bias2 + col);
      f32x4 v = acc2[mt][nt] + b2v;
      *(f32x4*)(out + (size_t)row * 512 + col) = v;
    }
  }

  // ---- trace: block-local, deterministic (no global atomics) ----
  #pragma unroll
  for (int mt = 0; mt < 4; ++mt) {
    tr[mt] += __shfl_xor(tr[mt], 16);
    tr[mt] += __shfl_xor(tr[mt], 32);
  }
  if (q == 0) {
    #pragma unroll
    for (int mt = 0; mt < 4; ++mt) redbuf[w][mt * 16 + m16] = tr[mt];
  }
  __syncthreads();
  if (tid < 64) {
    float s = 0.f;
    #pragma unroll
    for (int ww = 0; ww < 8; ++ww) s += redbuf[ww][tid];
    dlogp[bm * 64 + tid] = -s;
  }

  // ---- flush borderline list: ONE device atomic per block ----
  if (tid == 0) {
    uint32_t n = lcnt < LCAP ? lcnt : LCAP;
    lbase = atomicAdd(counter, n);
  }
  __syncthreads();
  uint32_t n = lcnt < LCAP ? lcnt : LCAP;
  uint32_t base = lbase;
  for (uint32_t i = tid; i < n; i += 512) {
    uint32_t gi = base + i;
    if (gi < LIST_CAP) list[gi] = llist[i];
  }
}

// ---------------- fixup: recompute borderline h_pre in fp32, patch dlogp ----------------
__global__ __launch_bounds__(256)
void fixup_kernel(const float* __restrict__ z, const float* __restrict__ W1,
                  const float* __restrict__ bias1, const float* __restrict__ cvec,
                  const uint32_t* __restrict__ list, const uint32_t* __restrict__ counter,
                  float* __restrict__ dlogp) {
  uint32_t cnt = *counter;
  if (cnt > LIST_CAP) cnt = LIST_CAP;
  const int wid = (blockIdx.x * 256 + threadIdx.x) >> 6;
  const int lane = threadIdx.x & 63;
  const int nw = gridDim.x * 4;
  for (uint32_t i = wid; i < cnt; i += nw) {
    uint32_t e = list[i];
    int row = (int)((e >> 10) & 16383u);
    int col = (int)(e & 1023u);
    int oldm = (int)(e >> 31);
    float s = 0.f;
    #pragma unroll
    for (int it = 0; it < 8; ++it) {
      int k = it * 64 + lane;
      s += z[(size_t)row * 512 + k] * W1[(size_t)col * 513 + k];
    }
    #pragma unroll
    for (int off = 32; off > 0; off >>= 1) s += __shfl_xor(s, off);
    if (lane == 0) {
      float hp = s + bias1[col];
      int newm = hp > 0.f ? 1 : 0;
      if (newm != oldm)
        atomicAdd(&dlogp[row], oldm ? cvec[col] : -cvec[col]);
    }
  }
}

// ---------------- launcher ----------------
extern "C" void kernel_launch(void* const* d_in, const int* in_sizes, int n_in,
                              void* d_out, int out_size, void* d_ws, size_t ws_size,
                              hipStream_t stream) {
  const float* t  = (const float*)d_in[0];
  const float* z  = (const float*)d_in[1];
  // d_in[2] = logp_z, unused
  const float* W1 = (const float*)d_in[3];
  const float* b1 = (const float*)d_in[4];
  const float* W2 = (const float*)d_in[5];
  const float* b2 = (const float*)d_in[6];

  float* out   = (float*)d_out;
  float* dlogp = out + (size_t)B_ * D_;

  char* ws = (char*)d_ws;
  _Float16* w1h   = (_Float16*)ws; ws += (size_t)N1_ * K1_ * 2;  // 1 MB
  _Float16* w2h   = (_Float16*)ws; ws += (size_t)N2_ * K2_ * 2;  // 1 MB
  float*    bias1 = (float*)ws;    ws += 1024 * 4;
  float*    bias2 = (float*)ws;    ws += 512 * 4;
  float*    cvec  = (float*)ws;    ws += 1024 * 4;
  uint32_t* counter = (uint32_t*)ws; ws += 256;
  uint32_t* list  = (uint32_t*)ws; ws += (size_t)LIST_CAP * 4;   // 8 MB

  prep_w<<<4356, 256, 0, stream>>>(t, W1, b1, W2, b2, w1h, w2h, bias1, bias2, cvec, counter);
  fused_kernel<<<256, 512, 0, stream>>>(z, w1h, w2h, bias1, bias2, cvec, out, dlogp, list, counter);
  fixup_kernel<<<2048, 256, 0, stream>>>(z, W1, bias1, cvec, list, counter, dlogp);
}